// Round 6
// baseline (147.111 us; speedup 1.0000x reference)
//
#include <hip/hip_runtime.h>

#define NIMG 16
#define H 512
#define W 512

// Streaming tile: 64 output rows x 128 output cols. 512 blocks (2/CU), 256 thr.
// Per step = one full-res row pair = one pooled chroma row. 46 steps/block.
// Staged cols: C0-16 .. C0+143 (160 = 40 quads). Pooled: C0/2-8 .. C0/2+71 (80).

// Raw barrier: order LDS ops only; do NOT drain vmcnt (prefetched global
// loads stay in flight across steps — __syncthreads would drain them).
static __device__ __forceinline__ void barln() {
    asm volatile("s_waitcnt lgkmcnt(0)" ::: "memory");
    __builtin_amdgcn_s_barrier();
    __builtin_amdgcn_sched_barrier(0);
}

// ---- issue 6 float4 loads for step px into named stash regs (no waits) ----
#define ISSUE(px, s0,s1,s2,s3,s4,s5) do { if (doLd) {                        \
    const int yy_ = 2*(px) + rr;                                             \
    const int yc_ = yy_ < 0 ? 0 : (yy_ > H-1 ? H-1 : yy_);                   \
    const size_t off_ = (size_t)yc_ * W + xcl;                               \
    s0 = *(const float4*)(pi + off_);                                        \
    s1 = *(const float4*)(pi + plane + off_);                                \
    s2 = *(const float4*)(pi + 2*plane + off_);                              \
    s3 = *(const float4*)(pt + off_);                                        \
    s4 = *(const float4*)(pt + plane + off_);                                \
    s5 = *(const float4*)(pt + 2*plane + off_);                              \
} } while(0)

// ---- consume stash of step px: diff -> dY quad + half-pooled U/V -> LDS ----
#define STAGE(px, s0,s1,s2,s3,s4,s5) do { if (doLd) {                        \
    const int yy_ = 2*(px) + rr;                                             \
    const float m_ = (cOK && (unsigned)yy_ < (unsigned)H) ? 1.f : 0.f;       \
    const int nb_ = (px) & 1;                                                \
    float4 dR_, dG_, dB_, y4_;                                               \
    dR_.x=(s0.x-s3.x)*m_; dR_.y=(s0.y-s3.y)*m_; dR_.z=(s0.z-s3.z)*m_; dR_.w=(s0.w-s3.w)*m_; \
    dG_.x=(s1.x-s4.x)*m_; dG_.y=(s1.y-s4.y)*m_; dG_.z=(s1.z-s4.z)*m_; dG_.w=(s1.w-s4.w)*m_; \
    dB_.x=(s2.x-s5.x)*m_; dB_.y=(s2.y-s5.y)*m_; dB_.z=(s2.z-s5.z)*m_; dB_.w=(s2.w-s5.w)*m_; \
    y4_.x = 0.299f*dR_.x + 0.587f*dG_.x + 0.114f*dB_.x;                      \
    y4_.y = 0.299f*dR_.y + 0.587f*dG_.y + 0.114f*dB_.y;                      \
    y4_.z = 0.299f*dR_.z + 0.587f*dG_.z + 0.114f*dB_.z;                      \
    y4_.w = 0.299f*dR_.w + 0.587f*dG_.w + 0.114f*dB_.w;                      \
    *(float4*)&dYb[nb_][rr][qq << 2] = y4_;                                  \
    const float rA_ = dR_.x+dR_.y, gA_ = dG_.x+dG_.y, bA_ = dB_.x+dB_.y;     \
    const float rB_ = dR_.z+dR_.w, gB_ = dG_.z+dG_.w, bB_ = dB_.z+dB_.w;     \
    *(float2*)&hUVb[nb_][rr][0][qq << 1] =                                   \
        make_float2(-0.169f*rA_ - 0.331f*gA_ + 0.5f*bA_,                     \
                    -0.169f*rB_ - 0.331f*gB_ + 0.5f*bB_);                    \
    *(float2*)&hUVb[nb_][rr][1][qq << 1] =                                   \
        make_float2( 0.5f*rA_ - 0.46f*gA_ - 0.04f*bA_,                       \
                     0.5f*rB_ - 0.46f*gB_ - 0.04f*bB_);                      \
} } while(0)

// ---- per-step compute: 15-tap hbox (regs) + vertical sliding sum + square.
// Rings are thread-private per column: no cross-thread ring sharing.
#define COMPUTE(px) do {                                                     \
    const int cb_ = (px) & 1;                                                \
    if (tid < 128) {                                                         \
        const float* r0_ = dYb[cb_][0];                                      \
        const float* r1_ = dYb[cb_][1];                                      \
        float hb0_ = 0.f, hb1_ = 0.f;                                        \
        _Pragma("unroll")                                                    \
        for (int j_ = 0; j_ < 15; ++j_) {                                    \
            hb0_ += r0_[tid + 9 + j_]; hb1_ += r1_[tid + 9 + j_];            \
        }                                                                    \
        const float rdA_ = ringY[(2*(px)+1) & 15][tid];                      \
        const float rdB_ = ringY[(2*(px)+2) & 15][tid];                      \
        svY += hb0_ - rdA_;                                                  \
        const int y0_ = 2*(px) - 7 - R0;                                     \
        if ((unsigned)y0_ < 64u) accY += svY * svY;                          \
        svY += hb1_ - rdB_;                                                  \
        if ((unsigned)(y0_ + 1) < 64u) accY += svY * svY;                    \
        ringY[(2*(px)) & 15][tid]     = hb0_;                                \
        ringY[(2*(px)+1) & 15][tid]   = hb1_;                                \
    } else {                                                                 \
        const int pl_ = (tid >> 6) & 1;                                      \
        const int cc_ = tid & 63;                                            \
        const float* h0_ = hUVb[cb_][0][pl_];                                \
        const float* h1_ = hUVb[cb_][1][pl_];                                \
        float hbC_ = 0.f;                                                    \
        _Pragma("unroll")                                                    \
        for (int j_ = 0; j_ < 15; ++j_)                                      \
            hbC_ += h0_[cc_ + 1 + j_] + h1_[cc_ + 1 + j_];                   \
        hbC_ *= 0.25f;                                                       \
        float (*rg_)[64] = pl_ ? ringV : ringU;                              \
        svC += hbC_ - rg_[((px)+1) & 15][cc_];                               \
        if ((unsigned)((px) - 7 - P0) < 32u) accC += svC * svC;              \
        rg_[(px) & 15][cc_] = hbC_;                                          \
    }                                                                        \
} while(0)

__global__ __launch_bounds__(256, 2) void fused_stream_kernel(
        const float* __restrict__ in, const float* __restrict__ tgt,
        float invY, float invC, float* __restrict__ partials) {
    __shared__ float dYb[2][2][160];        //  2.5 KB staging dbuf (dY rows)
    __shared__ float hUVb[2][2][2][80];     //  2.5 KB staging dbuf (half-pooled U/V per row)
    __shared__ float ringY[16][128];        //  8 KB hbox ring (luma)
    __shared__ float ringU[16][64];         //  4 KB
    __shared__ float ringV[16][64];         //  4 KB
    __shared__ float part[4];

    const int tid = threadIdx.x;
    const int b = blockIdx.x;
    const int n     = b >> 5;
    const int band  = (b >> 2) & 7;
    const int quart = b & 3;
    const int R0 = band << 6;
    const int C0 = quart << 7;
    const int P0 = band << 5;

    const size_t plane = (size_t)H * W;
    const float* pi = in  + (size_t)n * 3 * plane;
    const float* pt = tgt + (size_t)n * 3 * plane;

    // stage roles: threads 0..79 -> (row rr of pair, quad qq of 40)
    const bool doLd = tid < 80;
    const int rr = tid >= 40 ? 1 : 0;
    const int qq = tid - 40 * rr;
    const int xx = C0 - 16 + (qq << 2);     // full-res col of quad (4-aligned)
    const bool cOK = (unsigned)xx < (unsigned)W;
    const int xcl = cOK ? xx : 0;

    // zero rings (reads before first write must return 0 = zero padding)
    for (int i = tid; i < 16 * 128; i += 256) (&ringY[0][0])[i] = 0.f;
    for (int i = tid; i < 16 * 64; i += 256) {
        (&ringU[0][0])[i] = 0.f; (&ringV[0][0])[i] = 0.f;
    }

    float4 o0, o1, o2, o3, o4, o5;   // stash: odd-step loads
    float4 e0, e1, e2, e3, e4, e5;   // stash: even-step loads
    float svY = 0.f, svC = 0.f, accY = 0.f, accC = 0.f;

    const int pS = P0 - 7;           // always odd (P0 = 32*band)
    const int pE = P0 + 38;          // 46 steps

    // prologue: stage step pS, issue step pS+1
    ISSUE(pS, o0, o1, o2, o3, o4, o5);
    STAGE(pS, o0, o1, o2, o3, o4, o5);
    ISSUE(pS + 1, e0, e1, e2, e3, e4, e5);

#pragma unroll 1
    for (int p = pS; p <= pE; p += 2) {
        barln();                     // stage(p) visible; loads stay in flight
        if (p + 2 <= pE) ISSUE(p + 2, o0, o1, o2, o3, o4, o5);
        COMPUTE(p);
        STAGE(p + 1, e0, e1, e2, e3, e4, e5);   // waits loads issued 1 step ago
        barln();
        if (p + 3 <= pE) ISSUE(p + 3, e0, e1, e2, e3, e4, e5);
        COMPUTE(p + 1);
        if (p + 2 <= pE) STAGE(p + 2, o0, o1, o2, o3, o4, o5);
    }

    // ---- block reduction -> one partial per block ----
    float v = accY * invY + accC * invC;
    for (int o = 32; o > 0; o >>= 1) v += __shfl_down(v, o, 64);
    const int lane = tid & 63, wv = tid >> 6;
    if (lane == 0) part[wv] = v;
    __syncthreads();
    if (tid == 0)
        partials[b] = (part[0] + part[1]) + (part[2] + part[3]);
}

// ---------------------------------------------------------------------------
// Final: single-block sum of 512 partials -> out[0].
// ---------------------------------------------------------------------------
__global__ void final_reduce_kernel(const float* __restrict__ partials, int n,
                                    float* __restrict__ out) {
    float s = 0.f;
    for (int i = threadIdx.x; i < n; i += 256) s += partials[i];
    for (int o = 32; o > 0; o >>= 1) s += __shfl_down(s, o, 64);
    __shared__ float part[4];
    const int lane = threadIdx.x & 63, wid = threadIdx.x >> 6;
    if (lane == 0) part[wid] = s;
    __syncthreads();
    if (threadIdx.x == 0)
        *out = part[0] + part[1] + part[2] + part[3];
}

extern "C" void kernel_launch(void* const* d_in, const int* in_sizes, int n_in,
                              void* d_out, int out_size, void* d_ws, size_t ws_size,
                              hipStream_t stream) {
    const float* input  = (const float*)d_in[0];
    const float* target = (const float*)d_in[1];
    float* out = (float*)d_out;
    float* partials = (float*)d_ws;   // 512 floats

    const float invY = 1.0f / (float)((size_t)NIMG * H * W);            // 1/4194304
    const float invC = 1.0f / (float)((size_t)NIMG * (H/2) * (W/2));    // 1/1048576

    fused_stream_kernel<<<512, 256, 0, stream>>>(input, target, invY, invC, partials);
    final_reduce_kernel<<<1, 256, 0, stream>>>(partials, 512, out);
}

// Round 7
// 141.992 us; speedup vs baseline: 1.0361x; 1.0361x over previous
//
#include <hip/hip_runtime.h>

#define NIMG 16
#define H 512
#define W 512

// Raw barrier: orders LDS/shuffle ops only; does NOT drain vmcnt, so the
// prefetched global loads stay in flight across steps.
static __device__ __forceinline__ void barln() {
    asm volatile("s_waitcnt lgkmcnt(0)" ::: "memory");
    __builtin_amdgcn_s_barrier();
    __builtin_amdgcn_sched_barrier(0);
}

// Issue 12 scalar loads (2 rows x {in,tgt} x {R,G,B}) for row-pair p at col x.
// Rows clamped (masked to zero at consume); cols always in range (full width).
#define ISSUE(p, A0,A1,A2,A3,A4,A5,A6,A7,A8,A9,A10,A11) do {                 \
    const int ya_ = 2*(p);                                                   \
    const int yb_ = ya_ + 1;                                                 \
    const int yca_ = ya_ < 0 ? 0 : (ya_ > H-1 ? H-1 : ya_);                  \
    const int ycb_ = yb_ < 0 ? 0 : (yb_ > H-1 ? H-1 : yb_);                  \
    const size_t oa_ = (size_t)yca_ * W + x;                                 \
    const size_t ob_ = (size_t)ycb_ * W + x;                                 \
    A0 = pi[oa_];  A1 = pi[plane+oa_];  A2 = pi[2*plane+oa_];                \
    A3 = pt[oa_];  A4 = pt[plane+oa_];  A5 = pt[2*plane+oa_];                \
    A6 = pi[ob_];  A7 = pi[plane+ob_];  A8 = pi[2*plane+ob_];                \
    A9 = pt[ob_];  A10= pt[plane+ob_];  A11= pt[2*plane+ob_];                \
} while (0)

// ---------------------------------------------------------------------------
// Full-width streaming: block = 512 cols x 32-row band. Thread = one column.
// Per step (row pair): consume prefetched regs -> dY + pooled dU/dV ->
// wave prefix-scan hbox (shuffles; LDS only for 14 cross-wave edge lanes) ->
// thread-private vertical sliding sum vs 16-row LDS ring -> square-acc.
// One raw barrier/step; vmcnt never drained (continuous load stream).
// ---------------------------------------------------------------------------
__global__ __launch_bounds__(512, 2) void fused_row_kernel(
        const float* __restrict__ in, const float* __restrict__ tgt,
        float invY, float invC, float* __restrict__ partials) {
    __shared__ float ringY[16][512];      // 32 KB luma hbox ring
    __shared__ float ringC[16][512];      // 32 KB chroma ring (U even / V odd cols)
    __shared__ float LP[2][10][2][8];     // luma cross-wave prefix halos (per step parity)
    __shared__ float LS[2][10][2][8];     // luma suffix halos
    __shared__ float CP[2][10][16];       // chroma prefix halos
    __shared__ float CS[2][10][16];       // chroma suffix halos
    __shared__ float part[8];

    const int tid = threadIdx.x;
    // XCD swizzle: consecutive bands (sharing halo rows) land on the same XCD.
    const int idx  = (blockIdx.x & 7) * 32 + (blockIdx.x >> 3);
    const int n    = idx >> 4;
    const int band = idx & 15;
    const int R0 = band << 5;             // first output full-res row
    const int P0 = band << 4;             // first output pooled row

    const size_t plane = (size_t)H * W;
    const float* pi = in  + (size_t)n * 3 * plane;
    const float* pt = tgt + (size_t)n * 3 * plane;

    const int x = tid;                    // global column
    const int w = tid >> 6;               // wave 0..7
    const int l = tid & 63;               // lane

    // chroma plane coefficients by lane parity (even=U, odd=V)
    const bool ev = (l & 1) == 0;
    const float kr = ev ? -0.169f : 0.5f;
    const float kg = ev ? -0.331f : -0.46f;
    const float kb = ev ? 0.5f    : -0.04f;

    // zero rings + halos (reads before first write must return 0 = zero pad)
    for (int i = tid; i < 16 * 512; i += 512) {
        (&ringY[0][0])[i] = 0.f;
        (&ringC[0][0])[i] = 0.f;
    }
    if (tid < 320) {
        (&LP[0][0][0][0])[tid] = 0.f;
        (&LS[0][0][0][0])[tid] = 0.f;
        (&CP[0][0][0])[tid] = 0.f;
        (&CS[0][0][0])[tid] = 0.f;
    }
    __syncthreads();

    float svY = 0.f, svC = 0.f, accY = 0.f, accC = 0.f;

    // One full step: consume 12 stashed values for row-pair p, step parity sp.
    auto STEP = [&](int p, int sp,
                    float v0, float v1, float v2, float v3, float v4, float v5,
                    float v6, float v7, float v8, float v9, float v10, float v11) {
        const float ma = ((unsigned)(2 * p)     < (unsigned)H) ? 1.f : 0.f;
        const float mb = ((unsigned)(2 * p + 1) < (unsigned)H) ? 1.f : 0.f;
        const float dra = (v0 - v3) * ma, dga = (v1 - v4)  * ma, dba = (v2 - v5)  * ma;
        const float drb = (v6 - v9) * mb, dgb = (v7 - v10) * mb, dbb = (v8 - v11) * mb;
        float Q0 = 0.299f * dra + 0.587f * dga + 0.114f * dba;   // dY row 2p
        float Q1 = 0.299f * drb + 0.587f * dgb + 0.114f * dbb;   // dY row 2p+1
        const float hr = dra + drb, hg = dga + dgb, hb2 = dba + dbb;
        const float sr = hr  + __shfl_xor(hr, 1, 64);
        const float sg = hg  + __shfl_xor(hg, 1, 64);
        const float sb = hb2 + __shfl_xor(hb2, 1, 64);
        float Qc = (kr * sr + kg * sg + kb * sb) * 0.25f;        // pooled U/V by parity

        // in-wave inclusive prefix scans (luma: all lanes; chroma: stride-2)
#pragma unroll
        for (int d = 1; d <= 32; d <<= 1) {
            const float t0 = __shfl_up(Q0, d, 64);
            const float t1 = __shfl_up(Q1, d, 64);
            if (l >= d) { Q0 += t0; Q1 += t1; }
        }
#pragma unroll
        for (int d = 2; d <= 32; d <<= 1) {
            const float tc = __shfl_up(Qc, d, 64);
            if (l >= d) Qc += tc;
        }
        const float T0 = __shfl(Q0, 63, 64);
        const float T1 = __shfl(Q1, 63, 64);
        const float Tc = __shfl(Qc, 62 + (l & 1), 64);

        // cross-wave halo publish (14 lanes luma, 28 lanes chroma)
        if (l < 7) {
            LP[sp][w + 1][0][l] = Q0;  LP[sp][w + 1][1][l] = Q1;
        } else if (l >= 56 && l < 63) {
            LS[sp][w + 1][0][l - 56] = T0 - Q0;
            LS[sp][w + 1][1][l - 56] = T1 - Q1;
        }
        if (l < 14)                  CP[sp][w + 1][l]      = Qc;
        else if (l >= 48 && l < 62)  CS[sp][w + 1][l - 48] = Tc - Qc;

        barln();

        // 15-tap window sums from prefix differences + edge fixups
        const float d70 = __shfl_down(Q0, 7, 64);
        const float d71 = __shfl_down(Q1, 7, 64);
        const float u80 = __shfl_up(Q0, 8, 64);
        const float u81 = __shfl_up(Q1, 8, 64);
        float h0 = ((l <= 56) ? d70 : T0) - ((l >= 8) ? u80 : 0.f);
        float h1 = ((l <= 56) ? d71 : T1) - ((l >= 8) ? u81 : 0.f);
        if (l < 7)   { h0 += LS[sp][w][0][l];        h1 += LS[sp][w][1][l]; }
        if (l >= 57) { h0 += LP[sp][w + 2][0][l - 57]; h1 += LP[sp][w + 2][1][l - 57]; }
        const float dc = __shfl_down(Qc, 14, 64);
        const float uc = __shfl_up(Qc, 16, 64);
        float hc = ((l <= 49) ? dc : Tc) - ((l >= 16) ? uc : 0.f);
        if (l < 14)  hc += CS[sp][w][l];
        if (l >= 50) hc += CP[sp][w + 2][l - 50];

        // vertical sliding sums (thread-private column rings) + squares
        const int ra = 2 * p, rb = ra + 1;
        svY += h0 - ringY[(ra + 1) & 15][x];
        { const int o = ra - 7; if ((unsigned)(o - R0) < 32u) accY += svY * svY; }
        svY += h1 - ringY[(ra + 2) & 15][x];
        { const int o = rb - 7; if ((unsigned)(o - R0) < 32u) accY += svY * svY; }
        ringY[ra & 15][x] = h0;
        ringY[rb & 15][x] = h1;
        svC += hc - ringC[(p + 1) & 15][x];
        { const int oc = p - 7; if ((unsigned)(oc - P0) < 16u) accC += svC * svC; }
        ringC[p & 15][x] = hc;
    };

    // steps p = P0-7 .. P0+22 (30 steps), double-stashed prefetch A/B
    const int p0 = P0 - 7;
    float A0,A1,A2,A3,A4,A5,A6,A7,A8,A9,A10,A11;
    float B0,B1,B2,B3,B4,B5,B6,B7,B8,B9,B10,B11;
    ISSUE(p0, A0,A1,A2,A3,A4,A5,A6,A7,A8,A9,A10,A11);

#pragma unroll 1
    for (int it = 0; it < 15; ++it) {
        const int p = p0 + 2 * it;
        ISSUE(p + 1, B0,B1,B2,B3,B4,B5,B6,B7,B8,B9,B10,B11);
        STEP(p, 0, A0,A1,A2,A3,A4,A5,A6,A7,A8,A9,A10,A11);
        if (it < 14)
            ISSUE(p + 2, A0,A1,A2,A3,A4,A5,A6,A7,A8,A9,A10,A11);
        STEP(p + 1, 1, B0,B1,B2,B3,B4,B5,B6,B7,B8,B9,B10,B11);
    }

    // ---- block reduction -> one partial per block ----
    float v = accY * invY + accC * invC;
    for (int o = 32; o > 0; o >>= 1) v += __shfl_down(v, o, 64);
    if (l == 0) part[w] = v;
    __syncthreads();
    if (tid == 0) {
        float s = 0.f;
#pragma unroll
        for (int j = 0; j < 8; ++j) s += part[j];
        partials[blockIdx.x] = s;
    }
}

// ---------------------------------------------------------------------------
// Final: single-block sum of 256 partials -> out[0].
// ---------------------------------------------------------------------------
__global__ void final_reduce_kernel(const float* __restrict__ partials, int n,
                                    float* __restrict__ out) {
    float s = 0.f;
    for (int i = threadIdx.x; i < n; i += 256) s += partials[i];
    for (int o = 32; o > 0; o >>= 1) s += __shfl_down(s, o, 64);
    __shared__ float part[4];
    const int lane = threadIdx.x & 63, wid = threadIdx.x >> 6;
    if (lane == 0) part[wid] = s;
    __syncthreads();
    if (threadIdx.x == 0)
        *out = part[0] + part[1] + part[2] + part[3];
}

extern "C" void kernel_launch(void* const* d_in, const int* in_sizes, int n_in,
                              void* d_out, int out_size, void* d_ws, size_t ws_size,
                              hipStream_t stream) {
    const float* input  = (const float*)d_in[0];
    const float* target = (const float*)d_in[1];
    float* out = (float*)d_out;
    float* partials = (float*)d_ws;   // 256 floats

    const float invY = 1.0f / (float)((size_t)NIMG * H * W);            // 1/4194304
    const float invC = 1.0f / (float)((size_t)NIMG * (H/2) * (W/2));    // 1/1048576

    fused_row_kernel<<<256, 512, 0, stream>>>(input, target, invY, invC, partials);
    final_reduce_kernel<<<1, 256, 0, stream>>>(partials, 256, out);
}

// Round 8
// 139.939 us; speedup vs baseline: 1.0513x; 1.0147x over previous
//
#include <hip/hip_runtime.h>

#define NIMG 16
#define H 512
#define W 512

// ---------------------------------------------------------------------------
// Wave-autonomous fused kernel. ZERO barriers in the hot loop.
// wave = (img, band of 32 output rows, strip of 32 output cols).
// lane l -> full-res col x = 32*strip - 16 + l  (outputs at lanes 16..47).
// 30 fully-unrolled row-pair steps:
//   load 2 rows x {in,tgt} x {R,G,B} (12 scalar coalesced loads)
//   -> dY diffs + pooled dU/dV (lane-parity planes, xor-shuffle pooling)
//   -> vertical 15-row sliding sums against REGISTER rings (static indices)
//   -> horizontal 15-tap box via in-wave prefix scan (shfl_up) + P(l+7)-P(l-8)
//   -> square-accumulate.
// 4096 waves = 4 waves/SIMD on all 256 CUs, everything register-resident.
// ---------------------------------------------------------------------------
__global__ __launch_bounds__(256, 4) void fused_wave_kernel(
        const float* __restrict__ in, const float* __restrict__ tgt,
        float invY, float invC, float* __restrict__ partials) {
    __shared__ float part[4];

    const int tid = threadIdx.x;
    const int wv  = tid >> 6;
    const int l   = tid & 63;

    // XCD swizzle: each XCD owns 2 consecutive images (all their bands/strips)
    const int g     = (blockIdx.x & 7) * 128 + (blockIdx.x >> 3);
    const int n     = g >> 6;
    const int band  = (g >> 2) & 15;
    const int strip = ((g & 3) << 2) | wv;

    const size_t plane = (size_t)H * W;
    const float* pi = in  + (size_t)n * 3 * plane;
    const float* pt = tgt + (size_t)n * 3 * plane;

    const int x  = (strip << 5) - 16 + l;               // even base: pairs align
    const int xm = x < 0 ? 0 : (x > W - 1 ? W - 1 : x);
    const float mx = (x == xm) ? 1.f : 0.f;             // col zero-pad mask
    const float mL = (l >= 16 && l < 48) ? 1.f : 0.f;   // output-lane mask

    // chroma plane by lane parity (even = U, odd = V); +128 cancels in diff
    const bool ev = (l & 1) == 0;
    const float kr = ev ? -0.169f : 0.5f;
    const float kg = ev ? -0.331f : -0.46f;
    const float kb = ev ? 0.5f    : -0.04f;

    const int yBase = (band << 5) - 14;   // rows of pair q: yBase+2q, +1

    float ringA[8], ringB[8], ringC[16];  // register rings (literal indices)
#pragma unroll
    for (int i = 0; i < 8; ++i) { ringA[i] = 0.f; ringB[i] = 0.f; }
#pragma unroll
    for (int i = 0; i < 16; ++i) ringC[i] = 0.f;

    float V = 0.f, Vc = 0.f, accY = 0.f, accC = 0.f;

    // ---- one row-pair step; q is a compile-time literal everywhere ----
#define PAIR(q) do {                                                          \
    const int yA = yBase + 2*(q), yB = yA + 1;                                \
    const int yAc = yA < 0 ? 0 : (yA > H-1 ? H-1 : yA);                       \
    const int yBc = yB < 0 ? 0 : (yB > H-1 ? H-1 : yB);                       \
    const float mA = (yA == yAc) ? mx : 0.f;                                  \
    const float mB = (yB == yBc) ? mx : 0.f;                                  \
    const size_t oA = (size_t)yAc * W + xm;                                   \
    const size_t oB = (size_t)yBc * W + xm;                                   \
    const float irA = pi[oA], igA = pi[plane+oA], ibA = pi[2*plane+oA];       \
    const float trA = pt[oA], tgA = pt[plane+oA], tbA = pt[2*plane+oA];       \
    const float irB = pi[oB], igB = pi[plane+oB], ibB = pi[2*plane+oB];       \
    const float trB = pt[oB], tgB = pt[plane+oB], tbB = pt[2*plane+oB];       \
    const float drA = (irA-trA)*mA, dgA = (igA-tgA)*mA, dbA = (ibA-tbA)*mA;   \
    const float drB = (irB-trB)*mB, dgB = (igB-tgB)*mB, dbB = (ibB-tbB)*mB;   \
    const float dYA = 0.299f*drA + 0.587f*dgA + 0.114f*dbA;                   \
    const float dYB = 0.299f*drB + 0.587f*dgB + 0.114f*dbB;                   \
    const float Va = V + dYA - ringB[(q) & 7];      /* win15 ending yA */     \
    const float Vb = Va + dYB - ringA[((q)+1) & 7]; /* win15 ending yB */     \
    ringA[(q) & 7] = dYA;                                                     \
    ringB[(q) & 7] = dYB;                                                     \
    V = Vb;                                                                   \
    if ((q) >= 10 && (q) <= 26) {   /* some luma output this pair */          \
        float PA = Va, PB = Vb;                                               \
        _Pragma("unroll")                                                     \
        for (int d = 1; d <= 32; d <<= 1) {                                   \
            const float tA = __shfl_up(PA, d, 64);                            \
            const float tB = __shfl_up(PB, d, 64);                            \
            PA += (l >= d) ? tA : 0.f;                                        \
            PB += (l >= d) ? tB : 0.f;                                        \
        }                                                                     \
        const float hA = __shfl_down(PA, 7, 64) - __shfl_up(PA, 8, 64);       \
        const float hB = __shfl_down(PB, 7, 64) - __shfl_up(PB, 8, 64);       \
        if ((q) >= 11) accY += hA * hA * mL;   /* y_out = yA-7 in band */     \
        if ((q) <= 25) accY += hB * hB * mL;   /* y_out = yB-7 in band */     \
    }                                                                         \
    const float hr = drA + drB, hg = dgA + dgB, hb = dbA + dbB;               \
    const float sr = hr + __shfl_xor(hr, 1, 64);                              \
    const float sg = hg + __shfl_xor(hg, 1, 64);                              \
    const float sb = hb + __shfl_xor(hb, 1, 64);                              \
    const float Qc = (kr*sr + kg*sg + kb*sb) * 0.25f;                         \
    Vc += Qc - ringC[((q)+1) & 15];                                           \
    ringC[(q) & 15] = Qc;                                                     \
    if ((q) >= 14 && (q) <= 29) {   /* chroma output this pair */             \
        float PC = Vc;                                                        \
        _Pragma("unroll")                                                     \
        for (int d = 2; d <= 32; d <<= 1) {                                   \
            const float tC = __shfl_up(PC, d, 64);                            \
            PC += (l >= d) ? tC : 0.f;                                        \
        }                                                                     \
        const float hc = __shfl_down(PC, 14, 64) - __shfl_up(PC, 16, 64);     \
        accC += hc * hc * mL;                                                 \
    }                                                                         \
} while (0)

    PAIR(0);  PAIR(1);  PAIR(2);  PAIR(3);  PAIR(4);  PAIR(5);
    PAIR(6);  PAIR(7);  PAIR(8);  PAIR(9);  PAIR(10); PAIR(11);
    PAIR(12); PAIR(13); PAIR(14); PAIR(15); PAIR(16); PAIR(17);
    PAIR(18); PAIR(19); PAIR(20); PAIR(21); PAIR(22); PAIR(23);
    PAIR(24); PAIR(25); PAIR(26); PAIR(27); PAIR(28); PAIR(29);
#undef PAIR

    // ---- reduce: wave shuffle -> 4 partials -> block partial ----
    float v = accY * invY + accC * invC;
    for (int o = 32; o > 0; o >>= 1) v += __shfl_down(v, o, 64);
    if (l == 0) part[wv] = v;
    __syncthreads();
    if (tid == 0)
        partials[blockIdx.x] = (part[0] + part[1]) + (part[2] + part[3]);
}

// ---------------------------------------------------------------------------
// Final: single-block sum of 1024 partials -> out[0].
// ---------------------------------------------------------------------------
__global__ void final_reduce_kernel(const float* __restrict__ partials, int n,
                                    float* __restrict__ out) {
    float s = 0.f;
    for (int i = threadIdx.x; i < n; i += 256) s += partials[i];
    for (int o = 32; o > 0; o >>= 1) s += __shfl_down(s, o, 64);
    __shared__ float part[4];
    const int lane = threadIdx.x & 63, wid = threadIdx.x >> 6;
    if (lane == 0) part[wid] = s;
    __syncthreads();
    if (threadIdx.x == 0)
        *out = part[0] + part[1] + part[2] + part[3];
}

extern "C" void kernel_launch(void* const* d_in, const int* in_sizes, int n_in,
                              void* d_out, int out_size, void* d_ws, size_t ws_size,
                              hipStream_t stream) {
    const float* input  = (const float*)d_in[0];
    const float* target = (const float*)d_in[1];
    float* out = (float*)d_out;
    float* partials = (float*)d_ws;   // 1024 floats

    const float invY = 1.0f / (float)((size_t)NIMG * H * W);            // 1/4194304
    const float invC = 1.0f / (float)((size_t)NIMG * (H/2) * (W/2));    // 1/1048576

    fused_wave_kernel<<<1024, 256, 0, stream>>>(input, target, invY, invC, partials);
    final_reduce_kernel<<<1, 256, 0, stream>>>(partials, 1024, out);
}

// Round 10
// 135.622 us; speedup vs baseline: 1.0847x; 1.0318x over previous
//
#include <hip/hip_runtime.h>

#define NIMG 16
#define H 512
#define W 512

// ---------------------------------------------------------------------------
// Wave-autonomous fused kernel, DS-pipe-minimal edition.
// wave = (img, band of 32 output rows, strip of 64 output cols).
// lane l holds full-res cols {x0, x0+1}, x0 = strip*64 - 32 + 2l (float2).
// Per row-pair (30 fully-unrolled steps):
//   float2 loads (12 VMEM, 8B/lane, depth-2 stash pipeline)
//   -> diffs -> dY (2 cols) + lane-local 2x2-pooled dU/dV
//   -> vertical 15-row sliding sums vs REGISTER rings (literal indices)
//   -> horizontal 15-tap box: pure-DPP wave scan (VALU only, no DS pipe)
//      + <=6 parallel ds_bpermute window fetches
//   -> masked square-accumulate.
// Zero barriers, zero LDS in hot loop.
// ---------------------------------------------------------------------------

template<int CTRL, int RM>
static __device__ __forceinline__ float dppadd(float v) {
    return v + __uint_as_float((unsigned)__builtin_amdgcn_update_dpp(
        0, (int)__float_as_uint(v), CTRL, RM, 0xF, true));
}

// canonical wave64 inclusive add-scan: row_shr 1,2,4,8 + row_bcast15/31
static __device__ __forceinline__ float scan64(float v) {
    v = dppadd<0x111, 0xF>(v);
    v = dppadd<0x112, 0xF>(v);
    v = dppadd<0x114, 0xF>(v);
    v = dppadd<0x118, 0xF>(v);
    v = dppadd<0x142, 0xA>(v);
    v = dppadd<0x143, 0xC>(v);
    return v;
}

static __device__ __forceinline__ float bpermf(int byteaddr, float v) {
    return __uint_as_float((unsigned)__builtin_amdgcn_ds_bpermute(
        byteaddr, (int)__float_as_uint(v)));
}

// ---- issue 12 float2 loads for pair q into stash set S (no waits) ----
#define LOADP(q, S) do {                                                     \
    const int yA_ = yBase + 2*(q);                                           \
    const int yB_ = yA_ + 1;                                                 \
    const int yAc_ = yA_ < 0 ? 0 : (yA_ > H-1 ? H-1 : yA_);                  \
    const int yBc_ = yB_ < 0 ? 0 : (yB_ > H-1 ? H-1 : yB_);                  \
    const size_t oA_ = (size_t)yAc_ * W + xcl;                               \
    const size_t oB_ = (size_t)yBc_ * W + xcl;                               \
    S##_0  = *(const float2*)(pi + oA_);                                     \
    S##_1  = *(const float2*)(pi + plane + oA_);                             \
    S##_2  = *(const float2*)(pi + 2*plane + oA_);                           \
    S##_3  = *(const float2*)(pt + oA_);                                     \
    S##_4  = *(const float2*)(pt + plane + oA_);                             \
    S##_5  = *(const float2*)(pt + 2*plane + oA_);                           \
    S##_6  = *(const float2*)(pi + oB_);                                     \
    S##_7  = *(const float2*)(pi + plane + oB_);                             \
    S##_8  = *(const float2*)(pi + 2*plane + oB_);                           \
    S##_9  = *(const float2*)(pt + oB_);                                     \
    S##_10 = *(const float2*)(pt + plane + oB_);                             \
    S##_11 = *(const float2*)(pt + 2*plane + oB_);                           \
} while (0)

// ---- consume stash set S for pair q (q is a literal everywhere) ----
#define CONS(q, S) do {                                                      \
    const int yA_ = yBase + 2*(q);                                           \
    const float mA_ = ((unsigned)yA_       < (unsigned)H) ? mx : 0.f;        \
    const float mB_ = ((unsigned)(yA_ + 1) < (unsigned)H) ? mx : 0.f;        \
    const float drA0_ = (S##_0.x - S##_3.x) * mA_;                           \
    const float drA1_ = (S##_0.y - S##_3.y) * mA_;                           \
    const float dgA0_ = (S##_1.x - S##_4.x) * mA_;                           \
    const float dgA1_ = (S##_1.y - S##_4.y) * mA_;                           \
    const float dbA0_ = (S##_2.x - S##_5.x) * mA_;                           \
    const float dbA1_ = (S##_2.y - S##_5.y) * mA_;                           \
    const float drB0_ = (S##_6.x - S##_9.x) * mB_;                           \
    const float drB1_ = (S##_6.y - S##_9.y) * mB_;                           \
    const float dgB0_ = (S##_7.x - S##_10.x) * mB_;                          \
    const float dgB1_ = (S##_7.y - S##_10.y) * mB_;                          \
    const float dbB0_ = (S##_8.x - S##_11.x) * mB_;                          \
    const float dbB1_ = (S##_8.y - S##_11.y) * mB_;                          \
    const float dYA0_ = 0.299f*drA0_ + 0.587f*dgA0_ + 0.114f*dbA0_;          \
    const float dYA1_ = 0.299f*drA1_ + 0.587f*dgA1_ + 0.114f*dbA1_;          \
    const float dYB0_ = 0.299f*drB0_ + 0.587f*dgB0_ + 0.114f*dbB0_;          \
    const float dYB1_ = 0.299f*drB1_ + 0.587f*dgB1_ + 0.114f*dbB1_;          \
    /* lane-local 2x2 pooled chroma (+128 cancels in diff) */                \
    const float sr_ = (drA0_ + drA1_) + (drB0_ + drB1_);                     \
    const float sg_ = (dgA0_ + dgA1_) + (dgB0_ + dgB1_);                     \
    const float sb_ = (dbA0_ + dbA1_) + (dbB0_ + dbB1_);                     \
    const float u_ = (-0.169f*sr_ - 0.331f*sg_ + 0.5f *sb_) * 0.25f;         \
    const float w_ = ( 0.5f  *sr_ - 0.46f *sg_ - 0.04f*sb_) * 0.25f;         \
    /* vertical 15-row sliding sums (register rings, literal indices) */     \
    const float VA0_ = V0 + dYA0_ - rB0[(q) & 7];                            \
    const float VB0_ = VA0_ + dYB0_ - rA0[((q)+1) & 7];                      \
    rA0[(q) & 7] = dYA0_;  rB0[(q) & 7] = dYB0_;  V0 = VB0_;                 \
    const float VA1_ = V1 + dYA1_ - rB1[(q) & 7];                            \
    const float VB1_ = VA1_ + dYB1_ - rA1[((q)+1) & 7];                      \
    rA1[(q) & 7] = dYA1_;  rB1[(q) & 7] = dYB1_;  V1 = VB1_;                 \
    const float VU_ = CU + u_ - rU[((q)+1) & 15];                            \
    rU[(q) & 15] = u_;  CU = VU_;                                            \
    const float VV_ = CV + w_ - rV[((q)+1) & 15];                            \
    rV[(q) & 15] = w_;  CV = VV_;                                            \
    /* horizontal 15-tap via DPP pair-scan + parallel bpermute fetches */    \
    if ((q) >= 11 && (q) <= 26) {   /* row yA-7 is a band output row */      \
        const float SA_ = scan64(VA0_ + VA1_);                               \
        const float h0_ = SA_ - VA1_ - bpermf(am8, SA_);                     \
        const float h1_ = h0_ + VA1_ - bpermf(am7, VA0_);                    \
        accY += (h0_ * h0_) * mH0 + (h1_ * h1_) * mH1;                       \
    }                                                                        \
    if ((q) >= 10 && (q) <= 25) {   /* row yB-7 is a band output row */      \
        const float SB_ = scan64(VB0_ + VB1_);                               \
        const float h0_ = SB_ - VB1_ - bpermf(am8, SB_);                     \
        const float h1_ = h0_ + VB1_ - bpermf(am7, VB0_);                    \
        accY += (h0_ * h0_) * mH0 + (h1_ * h1_) * mH1;                       \
    }                                                                        \
    if ((q) >= 14) {                /* pooled row q-7 is an output row */    \
        const float SU_ = scan64(VU_);                                       \
        const float hU_ = SU_ - bpermf(am15, SU_);                           \
        const float SV_ = scan64(VV_);                                       \
        const float hV_ = SV_ - bpermf(am15, SV_);                           \
        accC += (hU_ * hU_ + hV_ * hV_) * mC;                                \
    }                                                                        \
} while (0)

__global__ __launch_bounds__(256, 2) void fused_wave_kernel(
        const float* __restrict__ in, const float* __restrict__ tgt,
        float invY, float invC, float* __restrict__ partials) {
    __shared__ float part[4];

    const int tid = threadIdx.x;
    const int wv  = tid >> 6;
    const int l   = tid & 63;

    // XCD swizzle (bijective, 512 = 8*64): each XCD owns 2 whole images.
    const int g     = (blockIdx.x & 7) * 64 + (blockIdx.x >> 3);
    const int n     = g >> 5;
    const int band  = (g >> 1) & 15;
    const int strip = ((g & 1) << 2) | wv;

    const size_t plane = (size_t)H * W;
    const float* pi = in  + (size_t)n * 3 * plane;
    const float* pt = tgt + (size_t)n * 3 * plane;

    const int R0 = band << 5;
    const int yBase = R0 - 14;

    const int x0 = (strip << 6) - 32 + 2 * l;          // even
    const int xcl = x0 < 0 ? 0 : (x0 > W - 2 ? W - 2 : x0);
    const float mx = (x0 == xcl) ? 1.f : 0.f;          // col zero-pad mask

    // output-lane masks (trailing-window col mapping)
    const float mH0 = (l >= 20 && l <= 51) ? 1.f : 0.f;   // odd rel cols 1..63
    const float mH1 = (l >= 19 && l <= 50) ? 1.f : 0.f;   // even rel cols 0..62
    const float mC  = (l >= 23 && l <= 54) ? 1.f : 0.f;   // pooled cols 0..31

    // bpermute byte addresses (garbage wraps land only in masked lanes)
    const int am8  = (l - 8)  << 2;
    const int am7  = (l - 7)  << 2;
    const int am15 = (l - 15) << 2;

    // register rings (all literal-indexed)
    float rA0[8], rA1[8], rB0[8], rB1[8], rU[16], rV[16];
#pragma unroll
    for (int i = 0; i < 8; ++i) { rA0[i] = 0.f; rA1[i] = 0.f; rB0[i] = 0.f; rB1[i] = 0.f; }
#pragma unroll
    for (int i = 0; i < 16; ++i) { rU[i] = 0.f; rV[i] = 0.f; }

    float V0 = 0.f, V1 = 0.f, CU = 0.f, CV = 0.f;
    float accY = 0.f, accC = 0.f;

    float2 A_0,A_1,A_2,A_3,A_4,A_5,A_6,A_7,A_8,A_9,A_10,A_11;
    float2 B_0,B_1,B_2,B_3,B_4,B_5,B_6,B_7,B_8,B_9,B_10,B_11;

    // depth-2 stash pipeline, fully unrolled (30 pairs)
    LOADP(0, A);
    LOADP(1, B);
    CONS(0, A);  LOADP(2, A);   CONS(1, B);  LOADP(3, B);
    CONS(2, A);  LOADP(4, A);   CONS(3, B);  LOADP(5, B);
    CONS(4, A);  LOADP(6, A);   CONS(5, B);  LOADP(7, B);
    CONS(6, A);  LOADP(8, A);   CONS(7, B);  LOADP(9, B);
    CONS(8, A);  LOADP(10, A);  CONS(9, B);  LOADP(11, B);
    CONS(10, A); LOADP(12, A);  CONS(11, B); LOADP(13, B);
    CONS(12, A); LOADP(14, A);  CONS(13, B); LOADP(15, B);
    CONS(14, A); LOADP(16, A);  CONS(15, B); LOADP(17, B);
    CONS(16, A); LOADP(18, A);  CONS(17, B); LOADP(19, B);
    CONS(18, A); LOADP(20, A);  CONS(19, B); LOADP(21, B);
    CONS(20, A); LOADP(22, A);  CONS(21, B); LOADP(23, B);
    CONS(22, A); LOADP(24, A);  CONS(23, B); LOADP(25, B);
    CONS(24, A); LOADP(26, A);  CONS(25, B); LOADP(27, B);
    CONS(26, A); LOADP(28, A);  CONS(27, B); LOADP(29, B);
    CONS(28, A);                CONS(29, B);

    // ---- reduce: wave shuffle -> 4 partials -> block partial ----
    float v = accY * invY + accC * invC;
    for (int o = 32; o > 0; o >>= 1) v += __shfl_down(v, o, 64);
    if (l == 0) part[wv] = v;
    __syncthreads();
    if (tid == 0)
        partials[blockIdx.x] = (part[0] + part[1]) + (part[2] + part[3]);
}

// ---------------------------------------------------------------------------
// Final: single-block sum of 512 partials -> out[0].
// ---------------------------------------------------------------------------
__global__ void final_reduce_kernel(const float* __restrict__ partials, int np,
                                    float* __restrict__ out) {
    float s = 0.f;
    for (int i = threadIdx.x; i < np; i += 256) s += partials[i];
    for (int o = 32; o > 0; o >>= 1) s += __shfl_down(s, o, 64);
    __shared__ float part[4];
    const int lane = threadIdx.x & 63, wid = threadIdx.x >> 6;
    if (lane == 0) part[wid] = s;
    __syncthreads();
    if (threadIdx.x == 0)
        *out = part[0] + part[1] + part[2] + part[3];
}

extern "C" void kernel_launch(void* const* d_in, const int* in_sizes, int n_in,
                              void* d_out, int out_size, void* d_ws, size_t ws_size,
                              hipStream_t stream) {
    const float* input  = (const float*)d_in[0];
    const float* target = (const float*)d_in[1];
    float* out = (float*)d_out;
    float* partials = (float*)d_ws;   // 512 floats

    const float invY = 1.0f / (float)((size_t)NIMG * H * W);            // 1/4194304
    const float invC = 1.0f / (float)((size_t)NIMG * (H/2) * (W/2));    // 1/1048576

    fused_wave_kernel<<<512, 256, 0, stream>>>(input, target, invY, invC, partials);
    final_reduce_kernel<<<1, 256, 0, stream>>>(partials, 512, out);
}